// Round 1
// baseline (2681.267 us; speedup 1.0000x reference)
//
#include <hip/hip_runtime.h>
#include <math.h>

#define NN 50000
#define EE 1600000

__device__ __forceinline__ float neg_inf() { return __int_as_float(0xFF800000); }

// float atomic max via signed-max (for >=0) / unsigned-min (for <0). Valid for
// non-NaN values; init to -inf.
__device__ __forceinline__ void atomicMaxF(float* addr, float v) {
    if (v >= 0.0f) {
        atomicMax((int*)addr, __float_as_int(v));
    } else {
        atomicMin((unsigned int*)addr, (unsigned int)__float_as_int(v));
    }
}

// One block per node. Loads x row (128 floats) into LDS, each thread j computes
// f[n,j] = dot(x_row, W[:,j]), then per-head reduction for el/er via LDS.
__global__ void proj_kernel(const float* __restrict__ x, const float* __restrict__ W,
                            const float* __restrict__ al, const float* __restrict__ ar,
                            float* __restrict__ f, float* __restrict__ el, float* __restrict__ er,
                            int C, int D, int H) {
    __shared__ float xs[128];
    __shared__ float pl[128];
    __shared__ float pr[128];
    int n = blockIdx.x;
    int j = threadIdx.x;
    for (int k = j; k < 128; k += blockDim.x) xs[k] = x[n * 128 + k];
    __syncthreads();
    if (j < C) {
        float acc = 0.0f;
        #pragma unroll 8
        for (int k = 0; k < 128; ++k) acc += xs[k] * W[k * C + j];
        f[n * C + j] = acc;
        pl[j] = acc * al[j];
        pr[j] = acc * ar[j];
    }
    __syncthreads();
    if (j < H) {
        float sl = 0.0f, sr = 0.0f;
        for (int d = 0; d < D; ++d) { sl += pl[j * D + d]; sr += pr[j * D + d]; }
        el[n * H + j] = sl;
        er[n * H + j] = sr;
    }
}

__global__ void init_kernel(float* __restrict__ m, float* __restrict__ s,
                            float* __restrict__ out, int NH, int NC) {
    int i = blockIdx.x * blockDim.x + threadIdx.x;
    if (i < NH) { m[i] = neg_inf(); s[i] = 0.0f; }
    if (i < NC) out[i] = 0.0f;
}

// One thread per (edge, head): e = leaky_relu(el[src]+er[dst]); atomicMax m[dst,h].
__global__ void edge_max_kernel(const int* __restrict__ src, const int* __restrict__ dst,
                                const float* __restrict__ el, const float* __restrict__ er,
                                float* __restrict__ m, int H, int total) {
    int idx = blockIdx.x * blockDim.x + threadIdx.x;
    if (idx >= total) return;
    int e = idx / H;
    int h = idx - e * H;
    int sn = src[e], dn = dst[e];
    float v = el[sn * H + h] + er[dn * H + h];
    v = v > 0.0f ? v : 0.2f * v;
    atomicMaxF(&m[dn * H + h], v);
}

// Cp (=2^cpshift) lanes per edge; lane c < C handles output channel c.
// Accumulates unnormalized out[dst,c] += ee * f[src,c]; one lane per head adds s.
__global__ void edge_agg_kernel(const int* __restrict__ src, const int* __restrict__ dst,
                                const float* __restrict__ el, const float* __restrict__ er,
                                const float* __restrict__ m, const float* __restrict__ f,
                                float* __restrict__ s, float* __restrict__ out,
                                int C, int dshift, int H, int cpshift) {
    int gid = blockIdx.x * blockDim.x + threadIdx.x;
    int e = gid >> cpshift;
    int c = gid & ((1 << cpshift) - 1);
    if (e >= EE || c >= C) return;
    int h = c >> dshift;
    int sn = src[e], dn = dst[e];
    float v = el[sn * H + h] + er[dn * H + h];
    v = v > 0.0f ? v : 0.2f * v;
    float ee = __expf(v - m[dn * H + h]);
    atomicAdd(&out[dn * C + c], ee * f[sn * C + c]);
    if (c == (h << dshift)) atomicAdd(&s[dn * H + h], ee);
}

// out[n,c] = elu(out[n,c] / s[n, c/32]) for C=128, D=32, H=4. In-place safe.
__global__ void finish_kernel(float* __restrict__ out, const float* __restrict__ s, int NC) {
    int i = blockIdx.x * blockDim.x + threadIdx.x;
    if (i >= NC) return;
    int n = i >> 7;
    int c = i & 127;
    int h = c >> 5;
    float v = out[i] / s[n * 4 + h];
    out[i] = v > 0.0f ? v : expm1f(v);
}

// Layer 2 epilogue: normalize by s (H=1), then log_softmax over 40 classes.
// One wave (64 lanes) per node; lanes >=40 idle. In-place safe (out2 may == dst).
__global__ void logits_kernel(const float* __restrict__ out2, const float* __restrict__ s,
                              float* __restrict__ dst) {
    int n = blockIdx.x;
    int c = threadIdx.x;
    float v = (c < 40) ? out2[n * 40 + c] / s[n] : neg_inf();
    float mx = v;
    #pragma unroll
    for (int o = 32; o > 0; o >>= 1) mx = fmaxf(mx, __shfl_down(mx, o));
    mx = __shfl(mx, 0);
    float ex = (c < 40) ? __expf(v - mx) : 0.0f;
    float sm = ex;
    #pragma unroll
    for (int o = 32; o > 0; o >>= 1) sm += __shfl_down(sm, o);
    sm = __shfl(sm, 0);
    if (c < 40) dst[n * 40 + c] = v - mx - logf(sm);
}

extern "C" void kernel_launch(void* const* d_in, const int* in_sizes, int n_in,
                              void* d_out, int out_size, void* d_ws, size_t ws_size,
                              hipStream_t stream) {
    const float* x0  = (const float*)d_in[0];
    const int*   src = (const int*)d_in[1];
    const int*   dst = (const int*)d_in[2];
    const float* W0  = (const float*)d_in[3];
    const float* al0 = (const float*)d_in[4];
    const float* ar0 = (const float*)d_in[5];
    const float* W1  = (const float*)d_in[6];
    const float* al1 = (const float*)d_in[7];
    const float* ar1 = (const float*)d_in[8];
    const float* W2  = (const float*)d_in[9];
    const float* al2 = (const float*)d_in[10];
    const float* ar2 = (const float*)d_in[11];

    float* out = (float*)d_out;
    float* ws  = (float*)d_ws;

    float* f    = ws;                  // N*128 = 6.4M floats
    float* h0   = ws + 6400000;        // N*128 = 6.4M
    float* el   = ws + 12800000;       // N*4
    float* er   = ws + 13000000;       // N*4
    float* m    = ws + 13200000;       // N*4
    float* sden = ws + 13400000;       // N*4

    float* logsm = out;                // [N,40]  (also used as layer-2 out buffer)
    float* h1    = out + 2000000;      // [N,128] (layer-1 output, is an output)
    float* out2  = logsm;              // layer-2 unnormalized accum (in-place finish)

    // ---------------- Layer 0: x0 -> h0 (ELU) ----------------
    proj_kernel<<<NN, 128, 0, stream>>>(x0, W0, al0, ar0, f, el, er, 128, 32, 4);
    init_kernel<<<(NN * 128 + 255) / 256, 256, 0, stream>>>(m, sden, h0, NN * 4, NN * 128);
    edge_max_kernel<<<(EE * 4 + 255) / 256, 256, 0, stream>>>(src, dst, el, er, m, 4, EE * 4);
    edge_agg_kernel<<<(EE * 128) / 256, 256, 0, stream>>>(src, dst, el, er, m, f, sden, h0, 128, 5, 4, 7);
    finish_kernel<<<(NN * 128 + 255) / 256, 256, 0, stream>>>(h0, sden, NN * 128);

    // ---------------- Layer 1: h0 -> h1 (ELU), h1 lives in d_out ----------------
    proj_kernel<<<NN, 128, 0, stream>>>(h0, W1, al1, ar1, f, el, er, 128, 32, 4);
    init_kernel<<<(NN * 128 + 255) / 256, 256, 0, stream>>>(m, sden, h1, NN * 4, NN * 128);
    edge_max_kernel<<<(EE * 4 + 255) / 256, 256, 0, stream>>>(src, dst, el, er, m, 4, EE * 4);
    edge_agg_kernel<<<(EE * 128) / 256, 256, 0, stream>>>(src, dst, el, er, m, f, sden, h1, 128, 5, 4, 7);
    finish_kernel<<<(NN * 128 + 255) / 256, 256, 0, stream>>>(h1, sden, NN * 128);

    // ---------------- Layer 2: h1 -> logits -> log_softmax ----------------
    proj_kernel<<<NN, 64, 0, stream>>>(h1, W2, al2, ar2, f, el, er, 40, 40, 1);
    init_kernel<<<(NN * 40 + 255) / 256, 256, 0, stream>>>(m, sden, out2, NN * 1, NN * 40);
    edge_max_kernel<<<(EE * 1 + 255) / 256, 256, 0, stream>>>(src, dst, el, er, m, 1, EE * 1);
    edge_agg_kernel<<<(EE * 64) / 256, 256, 0, stream>>>(src, dst, el, er, m, f, sden, out2, 40, 6, 1, 6);
    logits_kernel<<<NN, 64, 0, stream>>>(out2, sden, logsm);
}

// Round 2
// 1066.917 us; speedup vs baseline: 2.5131x; 2.5131x over previous
//
#include <hip/hip_runtime.h>
#include <math.h>

#define NN 50000
#define EE 1600000

// ---------------- CSR build (graph is shared by all 3 layers) ----------------

__global__ void csr_clear(int* __restrict__ deg) {
    int i = blockIdx.x * blockDim.x + threadIdx.x;
    if (i < NN) deg[i] = 0;
}

__global__ void csr_count(const int* __restrict__ dst, int* __restrict__ deg) {
    int e = blockIdx.x * blockDim.x + threadIdx.x;
    if (e < EE) atomicAdd(&deg[dst[e]], 1);
}

// Single-block exclusive scan over deg[NN] -> rowptr[NN+1], cursor (copy).
// 1024 threads, Hillis-Steele per 1024-chunk with running carry.
__global__ void csr_scan(const int* __restrict__ deg, int* __restrict__ rowptr,
                         int* __restrict__ cursor) {
    __shared__ int buf[1024];
    __shared__ int carry;
    int t = threadIdx.x;
    if (t == 0) carry = 0;
    __syncthreads();
    for (int base = 0; base < NN; base += 1024) {
        int i = base + t;
        int v = (i < NN) ? deg[i] : 0;
        buf[t] = v;
        __syncthreads();
        for (int off = 1; off < 1024; off <<= 1) {
            int add = (t >= off) ? buf[t - off] : 0;
            __syncthreads();
            buf[t] += add;
            __syncthreads();
        }
        int excl = carry + buf[t] - v;
        if (i < NN) { rowptr[i] = excl; cursor[i] = excl; }
        __syncthreads();
        if (t == 1023) carry += buf[1023];
        __syncthreads();
    }
    if (t == 0) rowptr[NN] = carry;
}

// NOTE: deg aliases cursor in the launch wrapper; csr_scan reads each element
// before overwriting it, so the aliasing is safe.

__global__ void csr_scatter(const int* __restrict__ src, const int* __restrict__ dst,
                            int* __restrict__ cursor, int* __restrict__ csr_src) {
    int e = blockIdx.x * blockDim.x + threadIdx.x;
    if (e >= EE) return;
    int pos = atomicAdd(&cursor[dst[e]], 1);
    csr_src[pos] = src[e];
}

// ---------------- Projection (unchanged from R0 — known correct) ----------------

__global__ void proj_kernel(const float* __restrict__ x, const float* __restrict__ W,
                            const float* __restrict__ al, const float* __restrict__ ar,
                            float* __restrict__ f, float* __restrict__ el, float* __restrict__ er,
                            int C, int D, int H) {
    __shared__ float xs[128];
    __shared__ float pl[128];
    __shared__ float pr[128];
    int n = blockIdx.x;
    int j = threadIdx.x;
    for (int k = j; k < 128; k += blockDim.x) xs[k] = x[n * 128 + k];
    __syncthreads();
    if (j < C) {
        float acc = 0.0f;
        #pragma unroll 8
        for (int k = 0; k < 128; ++k) acc += xs[k] * W[k * C + j];
        f[n * C + j] = acc;
        pl[j] = acc * al[j];
        pr[j] = acc * ar[j];
    }
    __syncthreads();
    if (j < H) {
        float sl = 0.0f, sr = 0.0f;
        for (int d = 0; d < D; ++d) { sl += pl[j * D + d]; sr += pr[j * D + d]; }
        el[n * H + j] = sl;
        er[n * H + j] = sr;
    }
}

// ---------------- Fused per-node aggregation, C=128 H=4 D=32 ----------------
// One 128-thread block per dst node. Phase A: per-head max over in-edges.
// Phase B: unnormalized accumulate + denom, then normalize + ELU. No atomics.
__global__ void agg128_kernel(const int* __restrict__ rowptr, const int* __restrict__ csr_src,
                              const float* __restrict__ el, const float* __restrict__ er,
                              const float* __restrict__ f, float* __restrict__ out) {
    int n = blockIdx.x;
    int t = threadIdx.x;                    // 128
    int start = rowptr[n], end = rowptr[n + 1];
    __shared__ float red[128];
    __shared__ float mx[4], ssum[4];

    // Phase A: thread t handles edge slots (t>>2) stride 32, head t&3.
    int h4 = t & 3;
    float lm = -INFINITY;
    for (int j = start + (t >> 2); j < end; j += 32) {
        int sn = csr_src[j];
        float v = el[sn * 4 + h4] + er[n * 4 + h4];
        v = v > 0.0f ? v : 0.2f * v;
        lm = fmaxf(lm, v);
    }
    red[t] = lm;
    __syncthreads();
    #pragma unroll
    for (int s = 64; s >= 4; s >>= 1) {
        if (t < s) red[t] = fmaxf(red[t], red[t + s]);
        __syncthreads();
    }
    if (t < 4) mx[t] = red[t];
    __syncthreads();

    // Phase B: thread t owns channel t, head t>>5.
    int h = t >> 5;
    float m_h = mx[h];
    float ern = er[n * 4 + h];
    float acc = 0.0f, sacc = 0.0f;
    for (int j = start; j < end; ++j) {
        int sn = csr_src[j];
        float v = el[sn * 4 + h] + ern;
        v = v > 0.0f ? v : 0.2f * v;
        float ee = __expf(v - m_h);
        sacc += ee;
        acc += ee * f[sn * 128 + t];
    }
    if ((t & 31) == 0) ssum[h] = sacc;      // all lanes of a head hold the same sacc
    __syncthreads();
    float o = acc / ssum[h];
    out[n * 128 + t] = o > 0.0f ? o : expm1f(o);
}

// ---------------- Layer-2 fused agg + log_softmax, C=40 H=1 ----------------
// One wave (64 lanes) per node.
__global__ void agg40_logsm_kernel(const int* __restrict__ rowptr, const int* __restrict__ csr_src,
                                   const float* __restrict__ el, const float* __restrict__ er,
                                   const float* __restrict__ f, float* __restrict__ out) {
    int n = blockIdx.x;
    int t = threadIdx.x;                    // 64
    int start = rowptr[n], end = rowptr[n + 1];
    float ern = er[n];

    float lm = -INFINITY;
    for (int j = start + t; j < end; j += 64) {
        float v = el[csr_src[j]] + ern;
        v = v > 0.0f ? v : 0.2f * v;
        lm = fmaxf(lm, v);
    }
    #pragma unroll
    for (int o = 32; o > 0; o >>= 1) lm = fmaxf(lm, __shfl_xor(lm, o));

    float acc = 0.0f, sacc = 0.0f;
    for (int j = start; j < end; ++j) {
        int sn = csr_src[j];
        float v = el[sn] + ern;
        v = v > 0.0f ? v : 0.2f * v;
        float ee = __expf(v - lm);
        sacc += ee;
        if (t < 40) acc += ee * f[sn * 40 + t];
    }
    float logit = (t < 40) ? acc / sacc : -INFINITY;

    float mx = logit;
    #pragma unroll
    for (int o = 32; o > 0; o >>= 1) mx = fmaxf(mx, __shfl_xor(mx, o));
    float ex = (t < 40) ? __expf(logit - mx) : 0.0f;
    float sm = ex;
    #pragma unroll
    for (int o = 32; o > 0; o >>= 1) sm += __shfl_xor(sm, o);
    if (t < 40) out[n * 40 + t] = logit - mx - logf(sm);
}

// ---------------- launch ----------------

extern "C" void kernel_launch(void* const* d_in, const int* in_sizes, int n_in,
                              void* d_out, int out_size, void* d_ws, size_t ws_size,
                              hipStream_t stream) {
    const float* x0  = (const float*)d_in[0];
    const int*   src = (const int*)d_in[1];
    const int*   dst = (const int*)d_in[2];
    const float* W0  = (const float*)d_in[3];
    const float* al0 = (const float*)d_in[4];
    const float* ar0 = (const float*)d_in[5];
    const float* W1  = (const float*)d_in[6];
    const float* al1 = (const float*)d_in[7];
    const float* ar1 = (const float*)d_in[8];
    const float* W2  = (const float*)d_in[9];
    const float* al2 = (const float*)d_in[10];
    const float* ar2 = (const float*)d_in[11];

    float* out = (float*)d_out;

    // int region first, then float region
    int* ipart   = (int*)d_ws;
    int* rowptr  = ipart;                    // NN+1
    int* cursor  = ipart + (NN + 1);         // NN (also deg)
    int* csr_src = ipart + (2 * NN + 1);     // EE
    float* fpart = (float*)(ipart + (2 * NN + 1 + EE));

    float* f  = fpart;                       // N*128
    float* h0 = fpart + 6400000;             // N*128
    float* el = fpart + 12800000;            // N*4
    float* er = fpart + 13000000;            // N*4

    float* logsm = out;                      // [N,40]
    float* h1    = out + 2000000;            // [N,128]

    // CSR build (deg aliases cursor; scan reads-before-writes each slot)
    csr_clear  <<<(NN + 255) / 256, 256, 0, stream>>>(cursor);
    csr_count  <<<(EE + 255) / 256, 256, 0, stream>>>(dst, cursor);
    csr_scan   <<<1, 1024, 0, stream>>>(cursor, rowptr, cursor);
    csr_scatter<<<(EE + 255) / 256, 256, 0, stream>>>(src, dst, cursor, csr_src);

    // Layer 0
    proj_kernel<<<NN, 128, 0, stream>>>(x0, W0, al0, ar0, f, el, er, 128, 32, 4);
    agg128_kernel<<<NN, 128, 0, stream>>>(rowptr, csr_src, el, er, f, h0);

    // Layer 1 (h1 lives in d_out)
    proj_kernel<<<NN, 128, 0, stream>>>(h0, W1, al1, ar1, f, el, er, 128, 32, 4);
    agg128_kernel<<<NN, 128, 0, stream>>>(rowptr, csr_src, el, er, f, h1);

    // Layer 2 (C=40, H=1) + fused log_softmax
    proj_kernel<<<NN, 64, 0, stream>>>(h1, W2, al2, ar2, f, el, er, 40, 40, 1);
    agg40_logsm_kernel<<<NN, 64, 0, stream>>>(rowptr, csr_src, el, er, f, logsm);
}

// Round 3
// 732.192 us; speedup vs baseline: 3.6620x; 1.4572x over previous
//
#include <hip/hip_runtime.h>
#include <hip/hip_fp16.h>
#include <math.h>

#define NN 50000
#define EE 1600000

// ---------------- CSR build (graph shared by all 3 layers) ----------------

__global__ void csr_clear(int* __restrict__ deg) {
    int i = blockIdx.x * blockDim.x + threadIdx.x;
    if (i < NN) deg[i] = 0;
}

__global__ void csr_count(const int* __restrict__ dst, int* __restrict__ deg) {
    int e = blockIdx.x * blockDim.x + threadIdx.x;
    if (e < EE) atomicAdd(&deg[dst[e]], 1);
}

// Device-wide exclusive scan, 3 kernels (NN=50000 -> 49 blocks of 1024).
__global__ void scan1(const int* __restrict__ deg, int* __restrict__ partial,
                      int* __restrict__ bsum) {
    __shared__ int buf[1024];
    int b = blockIdx.x, t = threadIdx.x;
    int i = b * 1024 + t;
    int v = (i < NN) ? deg[i] : 0;
    buf[t] = v;
    __syncthreads();
    for (int off = 1; off < 1024; off <<= 1) {
        int a = (t >= off) ? buf[t - off] : 0;
        __syncthreads();
        buf[t] += a;
        __syncthreads();
    }
    if (i < NN) partial[i] = buf[t] - v;   // exclusive within block
    if (t == 1023) bsum[b] = buf[1023];
}

__global__ void scan2(int* __restrict__ bsum, int nb) {
    if (threadIdx.x == 0) {
        int run = 0;
        for (int i = 0; i < nb; ++i) { int v = bsum[i]; bsum[i] = run; run += v; }
        bsum[nb] = run;
    }
}

__global__ void scan3(const int* __restrict__ partial, const int* __restrict__ bsum,
                      int* __restrict__ rowptr, int* __restrict__ cursor, int nb) {
    int i = blockIdx.x * blockDim.x + threadIdx.x;
    if (i < NN) {
        int r = partial[i] + bsum[i >> 10];
        rowptr[i] = r;
        cursor[i] = r;
    }
    if (i == 0) rowptr[NN] = bsum[nb];
}

__global__ void csr_scatter(const int* __restrict__ src, const int* __restrict__ dst,
                            int* __restrict__ cursor, int* __restrict__ csr_src) {
    int e = blockIdx.x * blockDim.x + threadIdx.x;
    if (e >= EE) return;
    int pos = atomicAdd(&cursor[dst[e]], 1);
    csr_src[pos] = src[e];
}

// ---------------- Projection (structure unchanged; f stored fp16) ----------------

__global__ void proj_kernel(const float* __restrict__ x, const float* __restrict__ W,
                            const float* __restrict__ al, const float* __restrict__ ar,
                            __half* __restrict__ f, float* __restrict__ el, float* __restrict__ er,
                            int C, int Cpad, int D, int H) {
    __shared__ float xs[128];
    __shared__ float pl[128];
    __shared__ float pr[128];
    int n = blockIdx.x;
    int j = threadIdx.x;
    for (int k = j; k < 128; k += blockDim.x) xs[k] = x[n * 128 + k];
    __syncthreads();
    if (j < C) {
        float acc = 0.0f;
        #pragma unroll 8
        for (int k = 0; k < 128; ++k) acc += xs[k] * W[k * C + j];
        f[n * Cpad + j] = __float2half(acc);
        pl[j] = acc * al[j];
        pr[j] = acc * ar[j];
    }
    __syncthreads();
    if (j < H) {
        float sl = 0.0f, sr = 0.0f;
        for (int d = 0; d < D; ++d) { sl += pl[j * D + d]; sr += pr[j * D + d]; }
        el[n * H + j] = sl;
        er[n * H + j] = sr;
    }
}

// ---------------- Fused per-node aggregation, C=128 H=4 D=32 ----------------
// One 128-thread block per dst node. Phase A: per-head max. Phase B: chunked
// ee precompute into LDS (expf once per edge-head), then gather-accumulate.
__global__ void agg128_kernel(const int* __restrict__ rowptr, const int* __restrict__ csr_src,
                              const float* __restrict__ el, const float* __restrict__ er,
                              const __half* __restrict__ f, float* __restrict__ out) {
    int n = blockIdx.x;
    int t = threadIdx.x;                    // 128
    int start = rowptr[n], end = rowptr[n + 1];
    __shared__ float red[128];
    __shared__ float mx[4];
    __shared__ float eebuf[32][4];
    __shared__ int snbuf[32];

    int slot = t >> 2, hh = t & 3;
    float erh = er[n * 4 + hh];

    // Phase A: per-head max over in-edges.
    float lm = -INFINITY;
    for (int j = start + slot; j < end; j += 32) {
        float v = el[csr_src[j] * 4 + hh] + erh;
        v = v > 0.0f ? v : 0.2f * v;
        lm = fmaxf(lm, v);
    }
    red[t] = lm;
    __syncthreads();
    #pragma unroll
    for (int s = 64; s >= 4; s >>= 1) {
        if (t < s) red[t] = fmaxf(red[t], red[t + s]);
        __syncthreads();
    }
    if (t < 4) mx[t] = red[t];
    __syncthreads();

    // Phase B: thread t owns channel t, head t>>5.
    int h = t >> 5;
    float m_hh = mx[hh];
    float acc = 0.0f, sacc = 0.0f;
    for (int base = start; base < end; base += 32) {
        int cnt = end - base;
        if (cnt > 32) cnt = 32;
        if (slot < cnt) {
            int sn = csr_src[base + slot];
            if (hh == 0) snbuf[slot] = sn;
            float v = el[sn * 4 + hh] + erh;
            v = v > 0.0f ? v : 0.2f * v;
            eebuf[slot][hh] = __expf(v - m_hh);
        }
        __syncthreads();
        for (int j = 0; j < cnt; ++j) {
            float ee = eebuf[j][h];
            sacc += ee;
            acc += ee * __half2float(f[snbuf[j] * 128 + t]);
        }
        __syncthreads();
    }
    float o = acc / sacc;
    out[n * 128 + t] = o > 0.0f ? o : expm1f(o);
}

// ---------------- Layer-2 fused agg + log_softmax, C=40 H=1 (rows padded to 64) --
__global__ void agg40_logsm_kernel(const int* __restrict__ rowptr, const int* __restrict__ csr_src,
                                   const float* __restrict__ el, const float* __restrict__ er,
                                   const __half* __restrict__ f, float* __restrict__ out) {
    int n = blockIdx.x;
    int t = threadIdx.x;                    // 64
    int start = rowptr[n], end = rowptr[n + 1];
    float ern = er[n];
    __shared__ float eebuf[64];
    __shared__ int snbuf[64];

    float lm = -INFINITY;
    for (int j = start + t; j < end; j += 64) {
        float v = el[csr_src[j]] + ern;
        v = v > 0.0f ? v : 0.2f * v;
        lm = fmaxf(lm, v);
    }
    #pragma unroll
    for (int o = 32; o > 0; o >>= 1) lm = fmaxf(lm, __shfl_xor(lm, o));

    float acc = 0.0f, sacc = 0.0f;
    for (int base = start; base < end; base += 64) {
        int cnt = end - base;
        if (cnt > 64) cnt = 64;
        if (t < cnt) {
            int sn = csr_src[base + t];
            snbuf[t] = sn;
            float v = el[sn] + ern;
            v = v > 0.0f ? v : 0.2f * v;
            eebuf[t] = __expf(v - lm);
        }
        __syncthreads();
        for (int j = 0; j < cnt; ++j) {
            float ee = eebuf[j];
            sacc += ee;
            if (t < 40) acc += ee * __half2float(f[snbuf[j] * 64 + t]);
        }
        __syncthreads();
    }
    float logit = (t < 40) ? acc / sacc : -INFINITY;

    float mx = logit;
    #pragma unroll
    for (int o = 32; o > 0; o >>= 1) mx = fmaxf(mx, __shfl_xor(mx, o));
    float ex = (t < 40) ? __expf(logit - mx) : 0.0f;
    float sm = ex;
    #pragma unroll
    for (int o = 32; o > 0; o >>= 1) sm += __shfl_xor(sm, o);
    if (t < 40) out[n * 40 + t] = logit - mx - logf(sm);
}

// ---------------- launch ----------------

extern "C" void kernel_launch(void* const* d_in, const int* in_sizes, int n_in,
                              void* d_out, int out_size, void* d_ws, size_t ws_size,
                              hipStream_t stream) {
    const float* x0  = (const float*)d_in[0];
    const int*   src = (const int*)d_in[1];
    const int*   dst = (const int*)d_in[2];
    const float* W0  = (const float*)d_in[3];
    const float* al0 = (const float*)d_in[4];
    const float* ar0 = (const float*)d_in[5];
    const float* W1  = (const float*)d_in[6];
    const float* al1 = (const float*)d_in[7];
    const float* ar1 = (const float*)d_in[8];
    const float* W2  = (const float*)d_in[9];
    const float* al2 = (const float*)d_in[10];
    const float* ar2 = (const float*)d_in[11];

    float* out = (float*)d_out;

    // int region (rounded to 16B multiple), then float region
    int* ipart   = (int*)d_ws;
    int* rowptr  = ipart;                        // NN+1
    int* cursor  = ipart + (NN + 1);             // NN
    int* csr_src = ipart + (2 * NN + 1);         // EE
    int* deg     = ipart + (2 * NN + 1 + EE);    // NN
    int* partial = deg + NN;                     // NN
    int* bsum    = partial + NN;                 // 64
    float* fpart = (float*)(ipart + 1850112);    // 16B-aligned float region

    __half* f16 = (__half*)fpart;                // N*128 halfs (= 3.2M floats)
    float* h0   = fpart + 3200000;               // N*128 fp32
    float* el   = fpart + 9600000;               // N*4
    float* er   = fpart + 9800000;               // N*4

    float* logsm = out;                          // [N,40]
    float* h1    = out + 2000000;                // [N,128]

    const int NB = (NN + 1023) / 1024;           // 49

    // CSR build
    csr_clear  <<<(NN + 255) / 256, 256, 0, stream>>>(deg);
    csr_count  <<<(EE + 255) / 256, 256, 0, stream>>>(dst, deg);
    scan1      <<<NB, 1024, 0, stream>>>(deg, partial, bsum);
    scan2      <<<1, 64, 0, stream>>>(bsum, NB);
    scan3      <<<(NN + 255) / 256, 256, 0, stream>>>(partial, bsum, rowptr, cursor, NB);
    csr_scatter<<<(EE + 255) / 256, 256, 0, stream>>>(src, dst, cursor, csr_src);

    // Layer 0
    proj_kernel<<<NN, 128, 0, stream>>>(x0, W0, al0, ar0, f16, el, er, 128, 128, 32, 4);
    agg128_kernel<<<NN, 128, 0, stream>>>(rowptr, csr_src, el, er, f16, h0);

    // Layer 1 (h1 lives in d_out)
    proj_kernel<<<NN, 128, 0, stream>>>(h0, W1, al1, ar1, f16, el, er, 128, 128, 32, 4);
    agg128_kernel<<<NN, 128, 0, stream>>>(rowptr, csr_src, el, er, f16, h1);

    // Layer 2 (C=40 padded to 64, H=1) + fused log_softmax
    proj_kernel<<<NN, 64, 0, stream>>>(h1, W2, al2, ar2, f16, el, er, 40, 64, 40, 1);
    agg40_logsm_kernel<<<NN, 64, 0, stream>>>(rowptr, csr_src, el, er, f16, logsm);
}

// Round 4
// 525.157 us; speedup vs baseline: 5.1057x; 1.3942x over previous
//
#include <hip/hip_runtime.h>
#include <hip/hip_fp16.h>
#include <math.h>

#define NN 50000
#define EE 1600000

typedef _Float16 f16x8 __attribute__((ext_vector_type(8)));
typedef _Float16 f16x4v __attribute__((ext_vector_type(4)));
typedef float f32x4 __attribute__((ext_vector_type(4)));

// ---------------- CSR build (graph shared by all 3 layers) ----------------

__global__ void csr_clear(int* __restrict__ deg) {
    int i = blockIdx.x * blockDim.x + threadIdx.x;
    if (i < NN) deg[i] = 0;
}

__global__ void csr_count(const int* __restrict__ dst, int* __restrict__ deg) {
    int e = blockIdx.x * blockDim.x + threadIdx.x;
    if (e < EE) atomicAdd(&deg[dst[e]], 1);
}

__global__ void scan1(const int* __restrict__ deg, int* __restrict__ partial,
                      int* __restrict__ bsum) {
    __shared__ int buf[1024];
    int b = blockIdx.x, t = threadIdx.x;
    int i = b * 1024 + t;
    int v = (i < NN) ? deg[i] : 0;
    buf[t] = v;
    __syncthreads();
    for (int off = 1; off < 1024; off <<= 1) {
        int a = (t >= off) ? buf[t - off] : 0;
        __syncthreads();
        buf[t] += a;
        __syncthreads();
    }
    if (i < NN) partial[i] = buf[t] - v;
    if (t == 1023) bsum[b] = buf[1023];
}

__global__ void scan2(int* __restrict__ bsum, int nb) {
    if (threadIdx.x == 0) {
        int run = 0;
        for (int i = 0; i < nb; ++i) { int v = bsum[i]; bsum[i] = run; run += v; }
        bsum[nb] = run;
    }
}

__global__ void scan3(const int* __restrict__ partial, const int* __restrict__ bsum,
                      int* __restrict__ rowptr, int* __restrict__ cursor, int nb) {
    int i = blockIdx.x * blockDim.x + threadIdx.x;
    if (i < NN) {
        int r = partial[i] + bsum[i >> 10];
        rowptr[i] = r;
        cursor[i] = r;
    }
    if (i == 0) rowptr[NN] = bsum[nb];
}

__global__ void csr_scatter(const int* __restrict__ src, const int* __restrict__ dst,
                            int* __restrict__ cursor, int* __restrict__ csr_src) {
    int e = blockIdx.x * blockDim.x + threadIdx.x;
    if (e >= EE) return;
    int pos = atomicAdd(&cursor[dst[e]], 1);
    csr_src[pos] = src[e];
}

// ---------------- input cast fp32 -> fp16 ----------------

__global__ void cast_x(const float* __restrict__ x, _Float16* __restrict__ y) {
    int i = blockIdx.x * blockDim.x + threadIdx.x;     // over NN*32 float4s
    if (i >= NN * 32) return;
    float4 v = ((const float4*)x)[i];
    f16x4v o;
    o.x = (_Float16)v.x; o.y = (_Float16)v.y; o.z = (_Float16)v.z; o.w = (_Float16)v.w;
    ((f16x4v*)y)[i] = o;
}

// ---------------- MFMA projection: f = x(fp16) @ W(fp32->fp16), + el/er ----------
// Block = 256 threads = 4 waves; each wave computes a 16-row x (CT*16)-col tile.
// W staged into LDS in B-fragment order: slot (ks,ct,lane) holds
// W[ks*32 + (lane>>4)*8 + j][ct*16 + (lane&15)], j=0..7 (k-contiguous per lane).
// A-frag: lane reads x[row=mrow+(lane&15)][ks*32 + (lane>>4)*8 + j] (contiguous).
// C/D: col = lane&15, row = (lane>>4)*4 + reg.
template<int CT, int CPAD, int CREAL, int HH, int CTPH>
__global__ void proj_mfma(const _Float16* __restrict__ x, const float* __restrict__ W,
                          const float* __restrict__ al, const float* __restrict__ ar,
                          _Float16* __restrict__ f, float* __restrict__ el,
                          float* __restrict__ er) {
    __shared__ _Float16 wl[4][CT][64][8];
    int lane = threadIdx.x & 63;
    int wave = threadIdx.x >> 6;
    int mrow = blockIdx.x * 64 + wave * 16;

    // Stage W -> LDS in fragment order (fp32 -> fp16 on the fly).
    for (int slot = threadIdx.x; slot < 4 * CT * 64; slot += 256) {
        int lane_s = slot & 63;
        int ct = (slot >> 6) % CT;
        int ks = (slot >> 6) / CT;
        int k0 = ks * 32 + ((lane_s >> 4) << 3);
        int c = ct * 16 + (lane_s & 15);
        f16x8 v;
        #pragma unroll
        for (int j = 0; j < 8; ++j) {
            float w = (c < CREAL) ? W[(k0 + j) * CREAL + c] : 0.0f;
            v[j] = (_Float16)w;
        }
        *(f16x8*)(&wl[ks][ct][lane_s][0]) = v;
    }
    __syncthreads();

    // A fragments (4 k-steps of 32).
    const _Float16* xrow = x + (size_t)(mrow + (lane & 15)) * 128 + ((lane >> 4) << 3);
    f16x8 a[4];
    #pragma unroll
    for (int ks = 0; ks < 4; ++ks) a[ks] = *(const f16x8*)(xrow + ks * 32);

    f32x4 acc[CT];
    #pragma unroll
    for (int ct = 0; ct < CT; ++ct) acc[ct] = (f32x4){0.f, 0.f, 0.f, 0.f};

    #pragma unroll
    for (int ct = 0; ct < CT; ++ct) {
        #pragma unroll
        for (int ks = 0; ks < 4; ++ks) {
            f16x8 b = *(const f16x8*)(&wl[ks][ct][lane][0]);
            acc[ct] = __builtin_amdgcn_mfma_f32_16x16x32_f16(a[ks], b, acc[ct], 0, 0, 0);
        }
    }

    int colb = lane & 15;
    int rowg = lane >> 4;

    // Store f (fp16).
    #pragma unroll
    for (int ct = 0; ct < CT; ++ct) {
        int c = ct * 16 + colb;
        #pragma unroll
        for (int j = 0; j < 4; ++j) {
            int r = rowg * 4 + j;
            f[(size_t)(mrow + r) * CPAD + c] = (_Float16)acc[ct][j];
        }
    }

    // el/er epilogue: per-head dot with al/ar, reduce across the 16-lane group.
    #pragma unroll
    for (int h = 0; h < HH; ++h) {
        float pl[4] = {0.f, 0.f, 0.f, 0.f};
        float pr[4] = {0.f, 0.f, 0.f, 0.f};
        #pragma unroll
        for (int q = 0; q < CTPH; ++q) {
            int ct = h * CTPH + q;
            int c = ct * 16 + colb;
            float av = (c < CREAL) ? al[c] : 0.0f;
            float rv = (c < CREAL) ? ar[c] : 0.0f;
            #pragma unroll
            for (int j = 0; j < 4; ++j) { pl[j] += acc[ct][j] * av; pr[j] += acc[ct][j] * rv; }
        }
        #pragma unroll
        for (int m = 1; m < 16; m <<= 1) {
            #pragma unroll
            for (int j = 0; j < 4; ++j) {
                pl[j] += __shfl_xor(pl[j], m);
                pr[j] += __shfl_xor(pr[j], m);
            }
        }
        if (colb == 0) {
            #pragma unroll
            for (int j = 0; j < 4; ++j) {
                int r = rowg * 4 + j;
                el[(size_t)(mrow + r) * HH + h] = pl[j];
                er[(size_t)(mrow + r) * HH + h] = pr[j];
            }
        }
    }
}

// ---------------- Fused per-node aggregation, C=128 H=4 D=32 ----------------
__global__ void agg128_kernel(const int* __restrict__ rowptr, const int* __restrict__ csr_src,
                              const float* __restrict__ el, const float* __restrict__ er,
                              const __half* __restrict__ f, _Float16* __restrict__ out16,
                              float* __restrict__ out32) {
    int n = blockIdx.x;
    int t = threadIdx.x;                    // 128
    int start = rowptr[n], end = rowptr[n + 1];
    __shared__ float red[128];
    __shared__ float mx[4];
    __shared__ float eebuf[32][4];
    __shared__ int snbuf[32];

    int slot = t >> 2, hh = t & 3;
    float erh = er[n * 4 + hh];

    float lm = -INFINITY;
    for (int j = start + slot; j < end; j += 32) {
        float v = el[csr_src[j] * 4 + hh] + erh;
        v = v > 0.0f ? v : 0.2f * v;
        lm = fmaxf(lm, v);
    }
    red[t] = lm;
    __syncthreads();
    #pragma unroll
    for (int s = 64; s >= 4; s >>= 1) {
        if (t < s) red[t] = fmaxf(red[t], red[t + s]);
        __syncthreads();
    }
    if (t < 4) mx[t] = red[t];
    __syncthreads();

    int h = t >> 5;
    float m_hh = mx[hh];
    float acc = 0.0f, sacc = 0.0f;
    for (int base = start; base < end; base += 32) {
        int cnt = end - base;
        if (cnt > 32) cnt = 32;
        if (slot < cnt) {
            int sn = csr_src[base + slot];
            if (hh == 0) snbuf[slot] = sn;
            float v = el[sn * 4 + hh] + erh;
            v = v > 0.0f ? v : 0.2f * v;
            eebuf[slot][hh] = __expf(v - m_hh);
        }
        __syncthreads();
        for (int j = 0; j < cnt; ++j) {
            float ee = eebuf[j][h];
            sacc += ee;
            acc += ee * __half2float(f[snbuf[j] * 128 + t]);
        }
        __syncthreads();
    }
    float o = acc / sacc;
    float e = o > 0.0f ? o : expm1f(o);
    out16[n * 128 + t] = (_Float16)e;
    if (out32) out32[n * 128 + t] = e;
}

// ---------------- Layer-2 fused agg + log_softmax, C=40 H=1 ----------------
__global__ void agg40_logsm_kernel(const int* __restrict__ rowptr, const int* __restrict__ csr_src,
                                   const float* __restrict__ el, const float* __restrict__ er,
                                   const __half* __restrict__ f, float* __restrict__ out) {
    int n = blockIdx.x;
    int t = threadIdx.x;                    // 64
    int start = rowptr[n], end = rowptr[n + 1];
    float ern = er[n];
    __shared__ float eebuf[64];
    __shared__ int snbuf[64];

    float lm = -INFINITY;
    for (int j = start + t; j < end; j += 64) {
        float v = el[csr_src[j]] + ern;
        v = v > 0.0f ? v : 0.2f * v;
        lm = fmaxf(lm, v);
    }
    #pragma unroll
    for (int o = 32; o > 0; o >>= 1) lm = fmaxf(lm, __shfl_xor(lm, o));

    float acc = 0.0f, sacc = 0.0f;
    for (int base = start; base < end; base += 64) {
        int cnt = end - base;
        if (cnt > 64) cnt = 64;
        if (t < cnt) {
            int sn = csr_src[base + t];
            snbuf[t] = sn;
            float v = el[sn] + ern;
            v = v > 0.0f ? v : 0.2f * v;
            eebuf[t] = __expf(v - lm);
        }
        __syncthreads();
        for (int j = 0; j < cnt; ++j) {
            float ee = eebuf[j];
            sacc += ee;
            if (t < 40) acc += ee * __half2float(f[snbuf[j] * 64 + t]);
        }
        __syncthreads();
    }
    float logit = (t < 40) ? acc / sacc : -INFINITY;

    float mx = logit;
    #pragma unroll
    for (int o = 32; o > 0; o >>= 1) mx = fmaxf(mx, __shfl_xor(mx, o));
    float ex = (t < 40) ? __expf(logit - mx) : 0.0f;
    float sm = ex;
    #pragma unroll
    for (int o = 32; o > 0; o >>= 1) sm += __shfl_xor(sm, o);
    if (t < 40) out[n * 40 + t] = logit - mx - logf(sm);
}

// ---------------- launch ----------------

extern "C" void kernel_launch(void* const* d_in, const int* in_sizes, int n_in,
                              void* d_out, int out_size, void* d_ws, size_t ws_size,
                              hipStream_t stream) {
    const float* x0  = (const float*)d_in[0];
    const int*   src = (const int*)d_in[1];
    const int*   dst = (const int*)d_in[2];
    const float* W0  = (const float*)d_in[3];
    const float* al0 = (const float*)d_in[4];
    const float* ar0 = (const float*)d_in[5];
    const float* W1  = (const float*)d_in[6];
    const float* al1 = (const float*)d_in[7];
    const float* ar1 = (const float*)d_in[8];
    const float* W2  = (const float*)d_in[9];
    const float* al2 = (const float*)d_in[10];
    const float* ar2 = (const float*)d_in[11];

    float* out = (float*)d_out;

    int* ipart   = (int*)d_ws;
    int* rowptr  = ipart;                        // NN+1
    int* cursor  = ipart + (NN + 1);             // NN
    int* csr_src = ipart + (2 * NN + 1);         // EE
    int* deg     = ipart + (2 * NN + 1 + EE);    // NN
    int* partial = deg + NN;                     // NN
    int* bsum    = partial + NN;                 // 64
    float* fpart = (float*)(ipart + 1850112);    // 16B-aligned float region

    _Float16* f16a = (_Float16*)fpart;                       // 50048*128 halves
    _Float16* x16  = (_Float16*)(fpart + 3203072);           // 50048*128 halves
    float* el      = fpart + 6406144;                        // 50048*4
    float* er      = fpart + 6606336;                        // 50048*4

    float* logsm = out;                          // [N,40]
    float* h1    = out + 2000000;                // [N,128]

    const int NB = (NN + 1023) / 1024;           // 49
    const int PB = (NN + 63) / 64;               // 782 proj blocks

    // CSR build
    csr_clear  <<<(NN + 255) / 256, 256, 0, stream>>>(deg);
    csr_count  <<<(EE + 255) / 256, 256, 0, stream>>>(dst, deg);
    scan1      <<<NB, 1024, 0, stream>>>(deg, partial, bsum);
    scan2      <<<1, 64, 0, stream>>>(bsum, NB);
    scan3      <<<(NN + 255) / 256, 256, 0, stream>>>(partial, bsum, rowptr, cursor, NB);
    csr_scatter<<<(EE + 255) / 256, 256, 0, stream>>>(src, dst, cursor, csr_src);

    // Layer 0
    cast_x<<<(NN * 32 + 255) / 256, 256, 0, stream>>>(x0, x16);
    proj_mfma<8, 128, 128, 4, 2><<<PB, 256, 0, stream>>>(x16, W0, al0, ar0, f16a, el, er);
    agg128_kernel<<<NN, 128, 0, stream>>>(rowptr, csr_src, el, er, (const __half*)f16a,
                                          x16, nullptr);               // h0 (fp16 in x16)

    // Layer 1 (h1 fp32 lives in d_out; fp16 copy back into x16)
    proj_mfma<8, 128, 128, 4, 2><<<PB, 256, 0, stream>>>(x16, W1, al1, ar1, f16a, el, er);
    agg128_kernel<<<NN, 128, 0, stream>>>(rowptr, csr_src, el, er, (const __half*)f16a,
                                          x16, h1);

    // Layer 2 (C=40 padded: CT=3 tiles, store rows padded to 64) + log_softmax
    proj_mfma<3, 64, 40, 1, 3><<<PB, 256, 0, stream>>>(x16, W2, al2, ar2, f16a, el, er);
    agg40_logsm_kernel<<<NN, 64, 0, stream>>>(rowptr, csr_src, el, er, (const __half*)f16a, logsm);
}

// Round 5
// 484.324 us; speedup vs baseline: 5.5361x; 1.0843x over previous
//
#include <hip/hip_runtime.h>
#include <hip/hip_fp16.h>
#include <math.h>

#define NN 50000
#define EE 1600000
#define NGRP 8
#define GRPSZ 6250   // NN / NGRP exactly

typedef _Float16 f16x8 __attribute__((ext_vector_type(8)));
typedef _Float16 f16x4v __attribute__((ext_vector_type(4)));
typedef float f32x4 __attribute__((ext_vector_type(4)));

// ---------------- CSR build (graph shared by all 3 layers) ----------------

__global__ void csr_clear(int* __restrict__ deg) {
    int i = blockIdx.x * blockDim.x + threadIdx.x;
    if (i < NN) deg[i] = 0;
}

// XCD-range-partitioned count: group g (= blockIdx&7 -> XCD g) only touches
// deg[] lines in its exclusive 6250-node range, so atomics stay L2-local.
__global__ void csr_count(const int* __restrict__ dst, int* __restrict__ deg) {
    int grp = blockIdx.x & 7;
    int lo = grp * GRPSZ, hi = lo + GRPSZ;
    int nblk = gridDim.x >> 3;
    int bi = blockIdx.x >> 3;
    for (int e = bi * blockDim.x + threadIdx.x; e < EE; e += nblk * blockDim.x) {
        int d = dst[e];
        if (d >= lo && d < hi) atomicAdd(&deg[d], 1);
    }
}

__global__ void scan1(const int* __restrict__ deg, int* __restrict__ partial,
                      int* __restrict__ bsum) {
    __shared__ int buf[1024];
    int b = blockIdx.x, t = threadIdx.x;
    int i = b * 1024 + t;
    int v = (i < NN) ? deg[i] : 0;
    buf[t] = v;
    __syncthreads();
    for (int off = 1; off < 1024; off <<= 1) {
        int a = (t >= off) ? buf[t - off] : 0;
        __syncthreads();
        buf[t] += a;
        __syncthreads();
    }
    if (i < NN) partial[i] = buf[t] - v;
    if (t == 1023) bsum[b] = buf[1023];
}

__global__ void scan2(int* __restrict__ bsum, int nb) {
    if (threadIdx.x == 0) {
        int run = 0;
        for (int i = 0; i < nb; ++i) { int v = bsum[i]; bsum[i] = run; run += v; }
        bsum[nb] = run;
    }
}

__global__ void scan3(const int* __restrict__ partial, const int* __restrict__ bsum,
                      int* __restrict__ rowptr, int* __restrict__ cursor, int nb) {
    int i = blockIdx.x * blockDim.x + threadIdx.x;
    if (i < NN) {
        int r = partial[i] + bsum[i >> 10];
        rowptr[i] = r;
        cursor[i] = r;
    }
    if (i == 0) rowptr[NN] = bsum[nb];
}

// XCD-range-partitioned scatter: group g only writes csr_src positions belonging
// to dst range [lo,hi) -> each 64B line of csr_src/cursor is written by exactly
// one XCD -> single write-back instead of ~16 partial-line flushes.
__global__ void csr_scatter(const int* __restrict__ src, const int* __restrict__ dst,
                            int* __restrict__ cursor, int* __restrict__ csr_src) {
    int grp = blockIdx.x & 7;
    int lo = grp * GRPSZ, hi = lo + GRPSZ;
    int nblk = gridDim.x >> 3;
    int bi = blockIdx.x >> 3;
    for (int e = bi * blockDim.x + threadIdx.x; e < EE; e += nblk * blockDim.x) {
        int d = dst[e];
        if (d >= lo && d < hi) {
            int pos = atomicAdd(&cursor[d], 1);
            csr_src[pos] = src[e];
        }
    }
}

// ---------------- input cast fp32 -> fp16 ----------------

__global__ void cast_x(const float* __restrict__ x, _Float16* __restrict__ y) {
    int i = blockIdx.x * blockDim.x + threadIdx.x;     // over NN*32 float4s
    if (i >= NN * 32) return;
    float4 v = ((const float4*)x)[i];
    f16x4v o;
    o.x = (_Float16)v.x; o.y = (_Float16)v.y; o.z = (_Float16)v.z; o.w = (_Float16)v.w;
    ((f16x4v*)y)[i] = o;
}

// ---------------- MFMA projection: f = x(fp16) @ W(fp32->fp16), + el/er ----------
template<int CT, int CPAD, int CREAL, int HH, int CTPH>
__global__ void proj_mfma(const _Float16* __restrict__ x, const float* __restrict__ W,
                          const float* __restrict__ al, const float* __restrict__ ar,
                          _Float16* __restrict__ f, float* __restrict__ el,
                          float* __restrict__ er) {
    __shared__ _Float16 wl[4][CT][64][8];
    int lane = threadIdx.x & 63;
    int wave = threadIdx.x >> 6;
    int mrow = blockIdx.x * 64 + wave * 16;

    for (int slot = threadIdx.x; slot < 4 * CT * 64; slot += 256) {
        int lane_s = slot & 63;
        int ct = (slot >> 6) % CT;
        int ks = (slot >> 6) / CT;
        int k0 = ks * 32 + ((lane_s >> 4) << 3);
        int c = ct * 16 + (lane_s & 15);
        f16x8 v;
        #pragma unroll
        for (int j = 0; j < 8; ++j) {
            float w = (c < CREAL) ? W[(k0 + j) * CREAL + c] : 0.0f;
            v[j] = (_Float16)w;
        }
        *(f16x8*)(&wl[ks][ct][lane_s][0]) = v;
    }
    __syncthreads();

    const _Float16* xrow = x + (size_t)(mrow + (lane & 15)) * 128 + ((lane >> 4) << 3);
    f16x8 a[4];
    #pragma unroll
    for (int ks = 0; ks < 4; ++ks) a[ks] = *(const f16x8*)(xrow + ks * 32);

    f32x4 acc[CT];
    #pragma unroll
    for (int ct = 0; ct < CT; ++ct) acc[ct] = (f32x4){0.f, 0.f, 0.f, 0.f};

    #pragma unroll
    for (int ct = 0; ct < CT; ++ct) {
        #pragma unroll
        for (int ks = 0; ks < 4; ++ks) {
            f16x8 b = *(const f16x8*)(&wl[ks][ct][lane][0]);
            acc[ct] = __builtin_amdgcn_mfma_f32_16x16x32_f16(a[ks], b, acc[ct], 0, 0, 0);
        }
    }

    int colb = lane & 15;
    int rowg = lane >> 4;

    #pragma unroll
    for (int ct = 0; ct < CT; ++ct) {
        int c = ct * 16 + colb;
        #pragma unroll
        for (int j = 0; j < 4; ++j) {
            int r = rowg * 4 + j;
            f[(size_t)(mrow + r) * CPAD + c] = (_Float16)acc[ct][j];
        }
    }

    #pragma unroll
    for (int h = 0; h < HH; ++h) {
        float pl[4] = {0.f, 0.f, 0.f, 0.f};
        float pr[4] = {0.f, 0.f, 0.f, 0.f};
        #pragma unroll
        for (int q = 0; q < CTPH; ++q) {
            int ct = h * CTPH + q;
            int c = ct * 16 + colb;
            float av = (c < CREAL) ? al[c] : 0.0f;
            float rv = (c < CREAL) ? ar[c] : 0.0f;
            #pragma unroll
            for (int j = 0; j < 4; ++j) { pl[j] += acc[ct][j] * av; pr[j] += acc[ct][j] * rv; }
        }
        #pragma unroll
        for (int m = 1; m < 16; m <<= 1) {
            #pragma unroll
            for (int j = 0; j < 4; ++j) {
                pl[j] += __shfl_xor(pl[j], m);
                pr[j] += __shfl_xor(pr[j], m);
            }
        }
        if (colb == 0) {
            #pragma unroll
            for (int j = 0; j < 4; ++j) {
                int r = rowg * 4 + j;
                el[(size_t)(mrow + r) * HH + h] = pl[j];
                er[(size_t)(mrow + r) * HH + h] = pr[j];
            }
        }
    }
}

// ---------------- Fused per-node aggregation, C=128 H=4 D=32 ----------------
__global__ void agg128_kernel(const int* __restrict__ rowptr, const int* __restrict__ csr_src,
                              const float* __restrict__ el, const float* __restrict__ er,
                              const __half* __restrict__ f, _Float16* __restrict__ out16,
                              float* __restrict__ out32) {
    int n = blockIdx.x;
    int t = threadIdx.x;                    // 128
    int start = rowptr[n], end = rowptr[n + 1];
    __shared__ float red[128];
    __shared__ float mx[4];
    __shared__ float eebuf[32][4];
    __shared__ int snbuf[32];

    int slot = t >> 2, hh = t & 3;
    float erh = er[n * 4 + hh];

    float lm = -INFINITY;
    for (int j = start + slot; j < end; j += 32) {
        float v = el[csr_src[j] * 4 + hh] + erh;
        v = v > 0.0f ? v : 0.2f * v;
        lm = fmaxf(lm, v);
    }
    red[t] = lm;
    __syncthreads();
    #pragma unroll
    for (int s = 64; s >= 4; s >>= 1) {
        if (t < s) red[t] = fmaxf(red[t], red[t + s]);
        __syncthreads();
    }
    if (t < 4) mx[t] = red[t];
    __syncthreads();

    int h = t >> 5;
    float m_hh = mx[hh];
    float acc = 0.0f, sacc = 0.0f;
    for (int base = start; base < end; base += 32) {
        int cnt = end - base;
        if (cnt > 32) cnt = 32;
        if (slot < cnt) {
            int sn = csr_src[base + slot];
            if (hh == 0) snbuf[slot] = sn;
            float v = el[sn * 4 + hh] + erh;
            v = v > 0.0f ? v : 0.2f * v;
            eebuf[slot][hh] = __expf(v - m_hh);
        }
        __syncthreads();
        for (int j = 0; j < cnt; ++j) {
            float ee = eebuf[j][h];
            sacc += ee;
            acc += ee * __half2float(f[snbuf[j] * 128 + t]);
        }
        __syncthreads();
    }
    float o = acc / sacc;
    float e = o > 0.0f ? o : expm1f(o);
    out16[n * 128 + t] = (_Float16)e;
    if (out32) out32[n * 128 + t] = e;
}

// ---------------- Layer-2 fused agg + log_softmax, C=40 H=1 ----------------
__global__ void agg40_logsm_kernel(const int* __restrict__ rowptr, const int* __restrict__ csr_src,
                                   const float* __restrict__ el, const float* __restrict__ er,
                                   const __half* __restrict__ f, float* __restrict__ out) {
    int n = blockIdx.x;
    int t = threadIdx.x;                    // 64
    int start = rowptr[n], end = rowptr[n + 1];
    float ern = er[n];
    __shared__ float eebuf[64];
    __shared__ int snbuf[64];

    float lm = -INFINITY;
    for (int j = start + t; j < end; j += 64) {
        float v = el[csr_src[j]] + ern;
        v = v > 0.0f ? v : 0.2f * v;
        lm = fmaxf(lm, v);
    }
    #pragma unroll
    for (int o = 32; o > 0; o >>= 1) lm = fmaxf(lm, __shfl_xor(lm, o));

    float acc = 0.0f, sacc = 0.0f;
    for (int base = start; base < end; base += 64) {
        int cnt = end - base;
        if (cnt > 64) cnt = 64;
        if (t < cnt) {
            int sn = csr_src[base + t];
            snbuf[t] = sn;
            float v = el[sn] + ern;
            v = v > 0.0f ? v : 0.2f * v;
            eebuf[t] = __expf(v - lm);
        }
        __syncthreads();
        for (int j = 0; j < cnt; ++j) {
            float ee = eebuf[j];
            sacc += ee;
            if (t < 40) acc += ee * __half2float(f[snbuf[j] * 64 + t]);
        }
        __syncthreads();
    }
    float logit = (t < 40) ? acc / sacc : -INFINITY;

    float mx = logit;
    #pragma unroll
    for (int o = 32; o > 0; o >>= 1) mx = fmaxf(mx, __shfl_xor(mx, o));
    float ex = (t < 40) ? __expf(logit - mx) : 0.0f;
    float sm = ex;
    #pragma unroll
    for (int o = 32; o > 0; o >>= 1) sm += __shfl_xor(sm, o);
    if (t < 40) out[n * 40 + t] = logit - mx - logf(sm);
}

// ---------------- launch ----------------

extern "C" void kernel_launch(void* const* d_in, const int* in_sizes, int n_in,
                              void* d_out, int out_size, void* d_ws, size_t ws_size,
                              hipStream_t stream) {
    const float* x0  = (const float*)d_in[0];
    const int*   src = (const int*)d_in[1];
    const int*   dst = (const int*)d_in[2];
    const float* W0  = (const float*)d_in[3];
    const float* al0 = (const float*)d_in[4];
    const float* ar0 = (const float*)d_in[5];
    const float* W1  = (const float*)d_in[6];
    const float* al1 = (const float*)d_in[7];
    const float* ar1 = (const float*)d_in[8];
    const float* W2  = (const float*)d_in[9];
    const float* al2 = (const float*)d_in[10];
    const float* ar2 = (const float*)d_in[11];

    float* out = (float*)d_out;

    int* ipart   = (int*)d_ws;
    int* rowptr  = ipart;                        // NN+1
    int* cursor  = ipart + (NN + 1);             // NN
    int* csr_src = ipart + (2 * NN + 1);         // EE
    int* deg     = ipart + (2 * NN + 1 + EE);    // NN
    int* partial = deg + NN;                     // NN
    int* bsum    = partial + NN;                 // 64
    float* fpart = (float*)(ipart + 1850112);    // 16B-aligned float region

    _Float16* f16a = (_Float16*)fpart;                       // 50048*128 halves
    _Float16* x16  = (_Float16*)(fpart + 3203072);           // 50048*128 halves
    float* el      = fpart + 6406144;                        // 50048*4
    float* er      = fpart + 6606336;                        // 50048*4

    float* logsm = out;                          // [N,40]
    float* h1    = out + 2000000;                // [N,128]

    const int NB = (NN + 1023) / 1024;           // 49
    const int PB = (NN + 63) / 64;               // 782 proj blocks

    // CSR build (count/scatter are XCD-range-partitioned: 8 groups x 128 blocks)
    csr_clear  <<<(NN + 255) / 256, 256, 0, stream>>>(deg);
    csr_count  <<<1024, 256, 0, stream>>>(dst, deg);
    scan1      <<<NB, 1024, 0, stream>>>(deg, partial, bsum);
    scan2      <<<1, 64, 0, stream>>>(bsum, NB);
    scan3      <<<(NN + 255) / 256, 256, 0, stream>>>(partial, bsum, rowptr, cursor, NB);
    csr_scatter<<<1024, 256, 0, stream>>>(src, dst, cursor, csr_src);

    // Layer 0
    cast_x<<<(NN * 32 + 255) / 256, 256, 0, stream>>>(x0, x16);
    proj_mfma<8, 128, 128, 4, 2><<<PB, 256, 0, stream>>>(x16, W0, al0, ar0, f16a, el, er);
    agg128_kernel<<<NN, 128, 0, stream>>>(rowptr, csr_src, el, er, (const __half*)f16a,
                                          x16, nullptr);               // h0 (fp16 in x16)

    // Layer 1 (h1 fp32 lives in d_out; fp16 copy back into x16)
    proj_mfma<8, 128, 128, 4, 2><<<PB, 256, 0, stream>>>(x16, W1, al1, ar1, f16a, el, er);
    agg128_kernel<<<NN, 128, 0, stream>>>(rowptr, csr_src, el, er, (const __half*)f16a,
                                          x16, h1);

    // Layer 2 (C=40 padded: CT=3 tiles, store rows padded to 64) + log_softmax
    proj_mfma<3, 64, 40, 1, 3><<<PB, 256, 0, stream>>>(x16, W2, al2, ar2, f16a, el, er);
    agg40_logsm_kernel<<<NN, 64, 0, stream>>>(rowptr, csr_src, el, er, (const __half*)f16a, logsm);
}